// Round 2
// baseline (340.691 us; speedup 1.0000x reference)
//
#include <hip/hip_runtime.h>
#include <hip/hip_fp16.h>
#include <hip/hip_cooperative_groups.h>

namespace cg = cooperative_groups;

#define NTOT   6422528   // 16*56*56*128
#define NPERB  401408    // 56*56*128
#define HH     56
#define WW     56
#define RS     7296      // guarded SAT row stride: 57*128
#define SB     415872    // guarded SAT per-sample: 57*57*128
#define LOG2E  1.4426950408889634f

__device__ __forceinline__ float sigmoidf_fast(float x) {
    return __builtin_amdgcn_rcpf(1.f + __expf(-x));
}

__device__ __forceinline__ void kappa_consts(const float* kap, float* dcs) {
    float v[5]; float mean = 0.f;
    for (int s = 0; s < 5; s++) {
        float lr = 0.6931471805599453f * (float)(s + 1);
        float k_ = 1.f / (1.f + expf(-kap[s]));
        float lk = 1.f / (1.f + expf(-logf(k_ + 1e-7f)));
        v[s] = lk + lr; mean += v[s];
    }
    mean *= 0.2f; float nd = 0.f;
    for (int s = 0; s < 5; s++) { float d = v[s] - mean; dcs[s] = d; nd += d * d; }
    dcs[5] = sqrtf(nd);
}

struct ScaleU { int rb1, rb0; float xmch; };

// =====================================================================
// Cooperative fused kernel: 448 blocks x 256 threads, 2 rows/cols per block.
// p: b = p&15 (p%8 = b&7 -> XCD affinity), u2 = p>>4 in [0,28).
// Needs only 1.75 blocks/CU co-resident; launch_bounds(256,2) + 60.5KB LDS
// guarantee >= 2 blocks/CU.
// =====================================================================
__launch_bounds__(256, 2)
__global__ void k_fused(const float* __restrict__ x,   const float* __restrict__ kap,
                        const float* __restrict__ W1,  const float* __restrict__ b1,
                        const float* __restrict__ W2,  const float* __restrict__ b2,
                        const float* __restrict__ gam, const float* __restrict__ bet,
                        const float* __restrict__ bnm, const float* __restrict__ bnv,
                        float* __restrict__ out, float* __restrict__ S,
                        float* __restrict__ sq, float* __restrict__ pmn,
                        float* __restrict__ pmx) {
    cg::grid_group grid = cg::this_grid();
    const int p = blockIdx.x;
    const int b = p & 15;
    const int u2 = p >> 4;           // [0,28)
    const int r0 = u2 * 2;
    const int tid = threadIdx.x;
    const int c = tid & 127, seg = tid >> 7;

    __shared__ unsigned int ABs[2 * 56 * 128];   // 56 KB: packed half2(A,B), 2 rows
    __shared__ float scr[512];
    __shared__ float tot[128];
    __shared__ float cst[9];                     // d0..d4, nd, xm, xi, xm*xi
    __shared__ float hid[16];
    __shared__ float exc[128];

    // ---------------- Phase 1: column prefixes j=r0,r0+1 + min/max ----------------
    {
        float mn = 3.4e38f, mx = -3.4e38f;
        for (int jj = 0; jj < 2; jj++) {
            const int j = r0 + jj;
            const int xbase = b * NPERB + j * 128 + c;
            const int scol  = b * SB + (j + 1) * 128 + c;
            float v[28];
            if (seg == 0) {
                S[scol] = 0.f;                          // guard row i=0
                if (j == 0) S[b * SB + c] = 0.f;        // guard corner (0,0)
                float acc = 0.f;
#pragma unroll
                for (int k = 0; k < 28; k++) {
                    float xv = x[xbase + k * 7168];
                    mn = fminf(mn, xv); mx = fmaxf(mx, xv);
                    acc += xv;
                    S[scol + (k + 1) * RS] = acc;
                }
                tot[c] = acc;
            } else {
                float acc = 0.f;
#pragma unroll
                for (int k = 0; k < 28; k++) {
                    float xv = x[xbase + (28 + k) * 7168];
                    mn = fminf(mn, xv); mx = fmaxf(mx, xv);
                    acc += xv;
                    v[k] = acc;
                }
            }
            __syncthreads();
            if (seg == 1) {
                float base = tot[c];
#pragma unroll
                for (int k = 0; k < 28; k++) S[scol + (29 + k) * RS] = base + v[k];
            }
            __syncthreads();
        }
        scr[tid] = mn; scr[256 + tid] = mx;
        __syncthreads();
        for (int s2 = 128; s2 > 0; s2 >>= 1) {
            if (tid < s2) {
                scr[tid]       = fminf(scr[tid],       scr[tid + s2]);
                scr[256 + tid] = fmaxf(scr[256 + tid], scr[256 + tid + s2]);
            }
            __syncthreads();
        }
        if (tid == 0) { pmn[p] = scr[0]; pmx[p] = scr[256]; }
        if (u2 == 0 && tid < 128) sq[b * 128 + tid] = 0.f;
    }

    grid.sync();

    // ---------------- Phase 2: row prefixes i=r0+1, r0+2 (guarded) ----------------
    for (int jj = 0; jj < 2; jj++) {
        const int i = r0 + 1 + jj;
        const int rowbase = b * SB + i * RS + c;
        float v[28];
        if (seg == 0) {
            S[rowbase] = 0.f;                       // guard col j=0
            float acc = 0.f;
#pragma unroll
            for (int k = 0; k < 28; k++) {
                acc += S[rowbase + (k + 1) * 128];
                S[rowbase + (k + 1) * 128] = acc;
            }
            tot[c] = acc;
        } else {
            float acc = 0.f;
#pragma unroll
            for (int k = 0; k < 28; k++) {
                acc += S[rowbase + (29 + k) * 128];
                v[k] = acc;
            }
        }
        __syncthreads();
        if (seg == 1) {
            float base = tot[c];
#pragma unroll
            for (int k = 0; k < 28; k++) S[rowbase + (29 + k) * 128] = base + v[k];
        }
        __syncthreads();
    }

    grid.sync();

    // ---------------- Phase 3: gather rows r0,r0+1 -> A/B in LDS + squeeze ----------------
    {
        if (tid < 64) {
            float mn2 = 3.4e38f, mx2 = -3.4e38f;
            if (tid < 28) { mn2 = pmn[b + 16 * tid]; mx2 = pmx[b + 16 * tid]; }
#pragma unroll
            for (int off = 32; off > 0; off >>= 1) {
                mn2 = fminf(mn2, __shfl_down(mn2, off));
                mx2 = fmaxf(mx2, __shfl_down(mx2, off));
            }
            if (tid == 0) {
                float xi = 1.f / (mx2 - mn2 + 1e-7f);
                cst[6] = mn2; cst[7] = xi; cst[8] = mn2 * xi;
            }
        } else if (tid == 64) {
            float d[6]; kappa_consts(kap, d);
#pragma unroll
            for (int s2 = 0; s2 < 6; s2++) cst[s2] = d[s2];
        }
        __syncthreads();

        const float* sp = S + b * SB + c;
        const float g = gam[c], be = bet[c], bm = bnm[c];
        const float rsv = rsqrtf(bnv[c] + 1e-3f);
        const float xm = cst[6], xi = cst[7], xmxi = cst[8];
        const float A1 = g * rsv, A0 = be - g * bm * rsv;
        const float C1 = -A1 * (LOG2E * 0.1f);
        const float C0 = -A0 * LOG2E;
        const float d0 = cst[0], d1 = cst[1], d2 = cst[2], d3 = cst[3], d4 = cst[4], nd = cst[5];

        float asum = 0.f;
        const int j0 = seg * 28;

        for (int rr = 0; rr < 2; rr++) {
            const int i = r0 + rr;

            auto mkU = [&](int hk) {
                ScaleU uu;
                int y1g = min(i + hk, HH - 1) + 1;
                int y0g = max(i - hk + 1, 0);
                uu.rb1 = y1g * RS; uu.rb0 = y0g * RS;
                uu.xmch = xm * (float)(y1g - y0g);
                return uu;
            };
            const ScaleU u0 = mkU(1), u1 = mkU(2), u2s = mkU(4), u3 = mkU(8), u4 = mkU(16);

            auto meas = [&](int j, const ScaleU& uu, int hk) -> float {
                int x1g = min(j + hk, WW - 1) + 1;
                int x0g = max(j - hk + 1, 0);
                float cw = (float)(x1g - x0g);
                int o1 = x1g << 7, o0 = x0g << 7;
                float s = sp[uu.rb1 + o1] - sp[uu.rb0 + o1] - sp[uu.rb1 + o0] + sp[uu.rb0 + o0];
                return __log2f(fmaxf((s - uu.xmch * cw) * xi, 0.f) + 1e-7f);
            };

            const float* xrow = x + b * NPERB + i * 7168 + c;
            for (int jj = 0; jj < 28; jj++) {
                int j = j0 + jj;
                float l0 = meas(j, u0, 1);
                float l1 = meas(j, u1, 2);
                float l2 = meas(j, u2s, 4);
                float l3 = meas(j, u3, 8);
                float l4 = meas(j, u4, 16);
                float w2 = -2.f * l0 - l1 + l3 + 2.f * l4;
                asum += w2;
                float alphas = w2 * 0.1f;
                float mean = 0.2f * (l0 + l1 + l2 + l3 + l4);
                float a0 = l0 - mean, a1 = l1 - mean, a2 = l2 - mean, a3 = l3 - mean, a4 = l4 - mean;
                float na2  = a0 * a0 + a1 * a1 + a2 * a2 + a3 * a3 + a4 * a4;
                float adot = a0 * d0 + a1 * d1 + a2 * d2 + a3 * d3 + a4 * d4;
                float na = __builtin_amdgcn_sqrtf(na2);
                float cosv = (alphas * adot) * __builtin_amdgcn_rcpf(na * fabsf(alphas) * nd + 1e-7f);
                float sim = 0.5f * (cosv + 1.f);
                float sbn = __builtin_amdgcn_rcpf(1.f + exp2f(C1 * w2 + C0));
                float xs = fmaf(xrow[j * 128], xi, -xmxi);
                float A = sim * sbn;
                float B = (1.f - sim) * xs;
                ABs[rr * 7168 + j * 128 + c] =
                    __builtin_bit_cast(unsigned int, __floats2half2_rn(A, B));
            }
        }
        asum *= 0.1f;
        scr[tid] = asum;
        __syncthreads();
        if (tid < 128) atomicAdd(&sq[b * 128 + tid], scr[tid] + scr[tid + 128]);
    }

    grid.sync();

    // ---------------- Phase 4: SE (redundant per block) + mix + store ----------------
    {
        if (tid < 128) scr[tid] = sq[b * 128 + tid] * (1.f / 3136.f);
        __syncthreads();
        if (tid < 16) {
            float acc = b1[tid];
            for (int c2 = 0; c2 < 128; c2++) acc += scr[c2] * W1[c2 * 16 + tid];
            hid[tid] = fmaxf(acc, 0.f);
        }
        __syncthreads();
        if (tid < 128) {
            float acc = b2[tid];
#pragma unroll
            for (int h = 0; h < 16; h++) acc += hid[h] * W2[h * 128 + tid];
            exc[tid] = sigmoidf_fast(acc);
        }
        __syncthreads();
        for (int rr = 0; rr < 2; rr++) {
            const int obase4 = (b * NPERB + (r0 + rr) * 7168) >> 2;
            const int abase  = rr * 7168;
            for (int t = tid; t < 1792; t += 256) {
                int j = t >> 5, c4 = (t & 31) << 2;
                uint4 uu = *reinterpret_cast<const uint4*>(&ABs[abase + j * 128 + c4]);
                float4 ev = *reinterpret_cast<const float4*>(&exc[c4]);
                float2 p0 = __half22float2(__builtin_bit_cast(__half2, uu.x));
                float2 p1 = __half22float2(__builtin_bit_cast(__half2, uu.y));
                float2 p2 = __half22float2(__builtin_bit_cast(__half2, uu.z));
                float2 p3 = __half22float2(__builtin_bit_cast(__half2, uu.w));
                reinterpret_cast<float4*>(out)[obase4 + t] =
                    make_float4(p0.x + p0.y * ev.x, p1.x + p1.y * ev.y,
                                p2.x + p2.y * ev.z, p3.x + p3.y * ev.w);
            }
        }
    }
}

// =====================================================================
// Fallback: proven 4-kernel pipeline (round-0 baseline, 150 us)
// =====================================================================
__global__ void k_colsum(const float* __restrict__ x, float* __restrict__ S,
                         float* __restrict__ pmn, float* __restrict__ pmx) {
    int p = blockIdx.x;
    int b = p / 56, j = p % 56;
    int c = threadIdx.x & 127, seg = threadIdx.x >> 7;
    int xbase = b * NPERB + j * 128 + c;
    int scol  = b * SB + (j + 1) * 128 + c;
    __shared__ float tot[128];
    __shared__ float rmn[256], rmx[256];
    float mn = 3.4e38f, mx = -3.4e38f;
    float v[28];
    if (seg == 0) {
        S[scol] = 0.f;
        if (j == 0) S[b * SB + c] = 0.f;
        float acc = 0.f;
#pragma unroll
        for (int k = 0; k < 28; k++) {
            float xv = x[xbase + k * 7168];
            mn = fminf(mn, xv); mx = fmaxf(mx, xv);
            acc += xv;
            S[scol + (k + 1) * RS] = acc;
        }
        tot[c] = acc;
    } else {
        float acc = 0.f;
#pragma unroll
        for (int k = 0; k < 28; k++) {
            float xv = x[xbase + (28 + k) * 7168];
            mn = fminf(mn, xv); mx = fmaxf(mx, xv);
            acc += xv;
            v[k] = acc;
        }
    }
    __syncthreads();
    if (seg == 1) {
        float base = tot[c];
#pragma unroll
        for (int k = 0; k < 28; k++) S[scol + (29 + k) * RS] = base + v[k];
    }
    rmn[threadIdx.x] = mn; rmx[threadIdx.x] = mx;
    __syncthreads();
    for (int s = 128; s > 0; s >>= 1) {
        if (threadIdx.x < s) {
            rmn[threadIdx.x] = fminf(rmn[threadIdx.x], rmn[threadIdx.x + s]);
            rmx[threadIdx.x] = fmaxf(rmx[threadIdx.x], rmx[threadIdx.x + s]);
        }
        __syncthreads();
    }
    if (threadIdx.x == 0) { pmn[p] = rmn[0]; pmx[p] = rmx[0]; }
}

__global__ void k_rowsum(float* __restrict__ S, const float* __restrict__ kap,
                         const float* __restrict__ pmn, const float* __restrict__ pmx,
                         float* __restrict__ xmn, float* __restrict__ xiv,
                         float* __restrict__ dcs, float* __restrict__ sq) {
    int p = blockIdx.x;
    if (p == 896) {
        int t = threadIdx.x;
        for (int k = t; k < 2048; k += 256) sq[k] = 0.f;
        if (t < 16) {
            float mn = 3.4e38f, mx = -3.4e38f;
            for (int k = 0; k < 56; k++) {
                mn = fminf(mn, pmn[t * 56 + k]);
                mx = fmaxf(mx, pmx[t * 56 + k]);
            }
            xmn[t] = mn;
            xiv[t] = 1.f / (mx - mn + 1e-7f);
        } else if (t == 32) kappa_consts(kap, dcs);
        return;
    }
    int b = p / 56, i = (p % 56) + 1;
    int c = threadIdx.x & 127, seg = threadIdx.x >> 7;
    int rowbase = b * SB + i * RS + c;
    __shared__ float tot[128];
    float v[28];
    if (seg == 0) {
        S[rowbase] = 0.f;
        float acc = 0.f;
#pragma unroll
        for (int k = 0; k < 28; k++) {
            acc += S[rowbase + (k + 1) * 128];
            S[rowbase + (k + 1) * 128] = acc;
        }
        tot[c] = acc;
    } else {
        float acc = 0.f;
#pragma unroll
        for (int k = 0; k < 28; k++) {
            acc += S[rowbase + (29 + k) * 128];
            v[k] = acc;
        }
    }
    __syncthreads();
    if (seg == 1) {
        float base = tot[c];
#pragma unroll
        for (int k = 0; k < 28; k++) S[rowbase + (29 + k) * 128] = base + v[k];
    }
}

__global__ void k_gather(const float* __restrict__ S, const float* __restrict__ x,
                         const float* __restrict__ gam, const float* __restrict__ bet,
                         const float* __restrict__ bnm, const float* __restrict__ bnv,
                         const float* __restrict__ xmn, const float* __restrict__ xiv,
                         const float* __restrict__ dcs, float* __restrict__ sq,
                         unsigned int* __restrict__ ABu) {
    int p_ = blockIdx.x;
    int L  = (p_ & 7) * 448 + (p_ >> 3);
    int b = L / 224, rem = L % 224;
    int i = rem >> 2, q = rem & 3;
    int c = threadIdx.x & 127, half = threadIdx.x >> 7;
    const float* sp = S + b * SB + c;
    float g = gam[c], be = bet[c], bm = bnm[c];
    float rs = rsqrtf(bnv[c] + 1e-3f);
    float xm = xmn[b], xi = xiv[b];
    float xmxi = xm * xi;
    float A1 = g * rs, A0 = be - g * bm * rs;
    float C1 = -A1 * (LOG2E * 0.1f);
    float C0 = -A0 * LOG2E;
    float d0 = dcs[0], d1 = dcs[1], d2 = dcs[2], d3 = dcs[3], d4 = dcs[4], nd = dcs[5];

    auto mkU = [&](int hk) {
        ScaleU u;
        int y1g = min(i + hk, HH - 1) + 1;
        int y0g = max(i - hk + 1, 0);
        u.rb1 = y1g * RS; u.rb0 = y0g * RS;
        u.xmch = xm * (float)(y1g - y0g);
        return u;
    };
    ScaleU u0 = mkU(1), u1 = mkU(2), u2 = mkU(4), u3 = mkU(8), u4 = mkU(16);

    auto meas = [&](int j, const ScaleU& u, int hk) -> float {
        int x1g = min(j + hk, WW - 1) + 1;
        int x0g = max(j - hk + 1, 0);
        float cw = (float)(x1g - x0g);
        int o1 = x1g << 7, o0 = x0g << 7;
        float s = sp[u.rb1 + o1] - sp[u.rb0 + o1] - sp[u.rb1 + o0] + sp[u.rb0 + o0];
        return __log2f(fmaxf((s - u.xmch * cw) * xi, 0.f) + 1e-7f);
    };

    float asum = 0.f;
    int j0 = q * 14 + half * 7;
    for (int jj = 0; jj < 7; jj++) {
        int j = j0 + jj;
        float l0 = meas(j, u0, 1);
        float l1 = meas(j, u1, 2);
        float l2 = meas(j, u2, 4);
        float l3 = meas(j, u3, 8);
        float l4 = meas(j, u4, 16);
        float w2 = -2.f * l0 - l1 + l3 + 2.f * l4;
        asum += w2;
        float alphas = w2 * 0.1f;
        float mean = 0.2f * (l0 + l1 + l2 + l3 + l4);
        float a0 = l0 - mean, a1 = l1 - mean, a2 = l2 - mean, a3 = l3 - mean, a4 = l4 - mean;
        float na2  = a0 * a0 + a1 * a1 + a2 * a2 + a3 * a3 + a4 * a4;
        float adot = a0 * d0 + a1 * d1 + a2 * d2 + a3 * d3 + a4 * d4;
        float na = __builtin_amdgcn_sqrtf(na2);
        float cosv = (alphas * adot) * __builtin_amdgcn_rcpf(na * fabsf(alphas) * nd + 1e-7f);
        float sim = 0.5f * (cosv + 1.f);
        float sbn = __builtin_amdgcn_rcpf(1.f + exp2f(C1 * w2 + C0));
        int idx = b * NPERB + i * 7168 + j * 128 + c;
        float xs = fmaf(x[idx], xi, -xmxi);
        float A = sim * sbn;
        float B = (1.f - sim) * xs;
        __half2 h2 = __floats2half2_rn(A, B);
        ABu[idx] = __builtin_bit_cast(unsigned int, h2);
    }
    asum *= 0.1f;
    __shared__ float red[256];
    red[threadIdx.x] = asum;
    __syncthreads();
    if (threadIdx.x < 128)
        atomicAdd(&sq[b * 128 + threadIdx.x], red[threadIdx.x] + red[threadIdx.x + 128]);
}

__launch_bounds__(256)
__global__ void k_mix(const unsigned int* __restrict__ ABu, const float* __restrict__ sq,
                      const float* __restrict__ W1, const float* __restrict__ b1,
                      const float* __restrict__ W2, const float* __restrict__ b2,
                      float* __restrict__ out) {
    __shared__ float buf[2048];
    __shared__ float hid[256];
    int tid = threadIdx.x;
    for (int k = tid; k < 2048; k += 256) buf[k] = sq[k] * (1.f / 3136.f);
    __syncthreads();
    {
        int bb = tid >> 4, h = tid & 15;
        float acc = b1[h];
        for (int c2 = 0; c2 < 128; c2++) acc += buf[bb * 128 + c2] * W1[c2 * 16 + h];
        hid[bb * 16 + h] = fmaxf(acc, 0.f);
    }
    __syncthreads();
    for (int k = tid; k < 2048; k += 256) {
        int bb = k >> 7, c2 = k & 127;
        float acc = b2[c2];
#pragma unroll
        for (int h = 0; h < 16; h++) acc += hid[bb * 16 + h] * W2[h * 128 + c2];
        buf[k] = sigmoidf_fast(acc);
    }
    __syncthreads();
    for (int t = blockIdx.x * 256 + tid; t < NTOT / 4; t += 1024 * 256) {
        int flat = t * 4;
        int b = flat / NPERB, cb = flat & 127;
        uint4 u = ((const uint4*)ABu)[t];
        float2 p0 = __half22float2(__builtin_bit_cast(__half2, u.x));
        float2 p1 = __half22float2(__builtin_bit_cast(__half2, u.y));
        float2 p2 = __half22float2(__builtin_bit_cast(__half2, u.z));
        float2 p3 = __half22float2(__builtin_bit_cast(__half2, u.w));
        ((float4*)out)[t] = make_float4(p0.x + p0.y * buf[b * 128 + cb],
                                        p1.x + p1.y * buf[b * 128 + cb + 1],
                                        p2.x + p2.y * buf[b * 128 + cb + 2],
                                        p3.x + p3.y * buf[b * 128 + cb + 3]);
    }
}

extern "C" void kernel_launch(void* const* d_in, const int* in_sizes, int n_in,
                              void* d_out, int out_size, void* d_ws, size_t ws_size,
                              hipStream_t stream) {
    const float* x   = (const float*)d_in[0];
    const float* kap = (const float*)d_in[1];
    const float* W1  = (const float*)d_in[2];
    const float* b1  = (const float*)d_in[3];
    const float* W2  = (const float*)d_in[4];
    const float* b2  = (const float*)d_in[5];
    const float* gam = (const float*)d_in[6];
    const float* bet = (const float*)d_in[7];
    const float* bnm = (const float*)d_in[8];
    const float* bnv = (const float*)d_in[9];
    float* out = (float*)d_out;

    float*        S   = (float*)d_ws;                   // 16*SB guarded SAT
    unsigned int* ABu = (unsigned int*)(S + 16 * SB);   // NTOT u32 (fallback only)
    float* sq  = (float*)(ABu + NTOT);                  // 2048
    float* pmn = sq + 2048;                             // 1024
    float* pmx = pmn + 1024;                            // 1024
    float* xmn = pmx + 1024;                            // 16
    float* xiv = xmn + 16;                              // 16
    float* dcs = xiv + 16;                              // 8

    void* args[] = {(void*)&x, (void*)&kap, (void*)&W1, (void*)&b1, (void*)&W2,
                    (void*)&b2, (void*)&gam, (void*)&bet, (void*)&bnm, (void*)&bnv,
                    (void*)&out, (void*)&S, (void*)&sq, (void*)&pmn, (void*)&pmx};
    hipError_t e = hipLaunchCooperativeKernel(reinterpret_cast<void*>(k_fused),
                                              dim3(448), dim3(256), args, 0, stream);
    if (e != hipSuccess) {
        (void)hipGetLastError();   // clear sticky error, use proven pipeline
        k_colsum<<<896, 256, 0, stream>>>(x, S, pmn, pmx);
        k_rowsum<<<897, 256, 0, stream>>>(S, kap, pmn, pmx, xmn, xiv, dcs, sq);
        k_gather<<<3584, 256, 0, stream>>>(S, x, gam, bet, bnm, bnv, xmn, xiv, dcs, sq, ABu);
        k_mix<<<1024, 256, 0, stream>>>(ABu, sq, W1, b1, W2, b2, out);
    }
}

// Round 3
// 149.756 us; speedup vs baseline: 2.2750x; 2.2750x over previous
//
#include <hip/hip_runtime.h>
#include <hip/hip_fp16.h>

#define NTOT   6422528   // 16*56*56*128
#define NPERB  401408    // 56*56*128
#define NQ     100352    // NPERB/4
#define LOG2E  1.4426950408889634f

__device__ __forceinline__ float sigmoidf_fast(float x) {
    return __builtin_amdgcn_rcpf(1.f + __expf(-x));
}

__device__ __forceinline__ unsigned encf(float f) {
    unsigned u = __float_as_uint(f);
    return (u & 0x80000000u) ? ~u : (u | 0x80000000u);
}
__device__ __forceinline__ float decf(unsigned u) {
    return __uint_as_float((u & 0x80000000u) ? (u ^ 0x80000000u) : ~u);
}

__device__ __forceinline__ void kappa_consts(const float* kap, float* dcs) {
    float v[5]; float mean = 0.f;
    for (int s = 0; s < 5; s++) {
        float lr = 0.6931471805599453f * (float)(s + 1);
        float k_ = 1.f / (1.f + expf(-kap[s]));
        float lk = 1.f / (1.f + expf(-logf(k_ + 1e-7f)));
        v[s] = lk + lr; mean += v[s];
    }
    mean *= 0.2f; float nd = 0.f;
    for (int s = 0; s < 5; s++) { float d = v[s] - mean; dcs[s] = d; nd += d * d; }
    dcs[5] = sqrtf(nd);
}

struct ScaleU { int rb1, rb0; float xmch; };

// ---------- K0: per-sample min/max (XCD-affine, warms L2 with x) ----------
// 512 blocks x 256: b = p&15 (XCD b%8), chunk = p>>4 in [0,32).
__global__ void k_minmax(const float4* __restrict__ x4,
                         unsigned* __restrict__ pmnu, unsigned* __restrict__ pmxu) {
    int p = blockIdx.x;
    int b = p & 15, chunk = p >> 4;
    const float4* base = x4 + b * NQ + chunk * 3136;
    float mn = 3.4e38f, mx = -3.4e38f;
    for (int q = threadIdx.x; q < 3136; q += 256) {
        float4 v = base[q];
        mn = fminf(mn, fminf(fminf(v.x, v.y), fminf(v.z, v.w)));
        mx = fmaxf(mx, fmaxf(fmaxf(v.x, v.y), fmaxf(v.z, v.w)));
    }
    __shared__ float rmn[256], rmx[256];
    int tid = threadIdx.x;
    rmn[tid] = mn; rmx[tid] = mx;
    __syncthreads();
    for (int s = 128; s > 0; s >>= 1) {
        if (tid < s) {
            rmn[tid] = fminf(rmn[tid], rmn[tid + s]);
            rmx[tid] = fmaxf(rmx[tid], rmx[tid + s]);
        }
        __syncthreads();
    }
    if (tid == 0) {
        atomicMin(&pmnu[b], encf(rmn[0]));
        atomicMax(&pmxu[b], encf(rmx[0]));
    }
}

// ---------- K1: SAT-in-LDS + gather. 256 blocks x 1024 threads ----------
// block p: b = p&15 (XCD b%8), cg = p>>4 -> channels [cg*8, cg*8+8).
// LDS SAT: 57 x 57 x 8 fp32 (guarded row 0 / col 0), 104 KB, 1 block/CU.
__launch_bounds__(1024)
__global__ void k_satg(const float* __restrict__ x,   const float* __restrict__ kap,
                       const float* __restrict__ gam, const float* __restrict__ bet,
                       const float* __restrict__ bnm, const float* __restrict__ bnv,
                       const unsigned* __restrict__ pmnu, const unsigned* __restrict__ pmxu,
                       float* __restrict__ sq, unsigned int* __restrict__ ABu) {
    __shared__ float SATl[57 * 57 * 8];   // (r*57 + col)*8 + cc
    __shared__ float tot[448];
    __shared__ float wsum[112];
    __shared__ float cst[9];              // d0..d4, nd, xm, xi, xm*xi

    const int p = blockIdx.x;
    const int b = p & 15, cg = p >> 4;
    const int c0 = cg * 8;
    const int tid = threadIdx.x;
    const int seg = (tid >= 448) ? 1 : 0;
    const int idx = tid - seg * 448;
    const int cc = idx & 7, lj = idx >> 3;   // lj: j (A1) / row-1 (A2) / i (A3)
    const bool act = (tid < 896);

    // guards: row 0 and col 0
    for (int z = tid; z < 456; z += 1024) SATl[z] = 0.f;
    for (int z = tid; z < 456; z += 1024) SATl[(z >> 3) * 456 + (z & 7)] = 0.f;

    float v[28];
    // ---- A1: load x + column prefix (rows) ----
    if (act) {
        const float* xp = x + b * NPERB + (seg * 28) * 7168 + lj * 128 + c0 + cc;
        float acc = 0.f;
#pragma unroll
        for (int k = 0; k < 28; k++) { acc += xp[k * 7168]; v[k] = acc; }
        if (seg == 0) {
#pragma unroll
            for (int k = 0; k < 28; k++) SATl[(k + 1) * 456 + (lj + 1) * 8 + cc] = v[k];
            tot[idx] = acc;
        }
    }
    __syncthreads();   // S1
    if (act && seg == 1) {
        float basev = tot[idx];
#pragma unroll
        for (int k = 0; k < 28; k++) SATl[(k + 29) * 456 + (lj + 1) * 8 + cc] = basev + v[k];
    }
    if (tid == 896) {              // idle threads compute block constants
        float d[6]; kappa_consts(kap, d);
        for (int s2 = 0; s2 < 6; s2++) cst[s2] = d[s2];
    } else if (tid == 897) {
        float mnv = decf(pmnu[b]), mxv = decf(pmxu[b]);
        float xi = 1.f / (mxv - mnv + 1e-7f);
        cst[6] = mnv; cst[7] = xi; cst[8] = mnv * xi;
    }
    __syncthreads();   // S2: column-prefix SAT complete, cst ready

    // ---- A2: row prefix (cols), in place ----
    if (act) {
        const int colbase = (lj + 1) * 456 + cc;
#pragma unroll
        for (int k = 0; k < 28; k++) v[k] = SATl[colbase + (seg * 28 + 1 + k) * 8];
#pragma unroll
        for (int k = 1; k < 28; k++) v[k] += v[k - 1];
        if (seg == 0) {
#pragma unroll
            for (int k = 0; k < 28; k++) SATl[colbase + (1 + k) * 8] = v[k];
            tot[idx] = v[27];
        }
    }
    __syncthreads();   // S3
    if (act && seg == 1) {
        const int colbase = (lj + 1) * 456 + cc;
        float basev = tot[idx];
#pragma unroll
        for (int k = 0; k < 28; k++) SATl[colbase + (29 + k) * 8] = basev + v[k];
    }
    __syncthreads();   // S4: full SAT ready

    // ---- A3: gather -> pack A/B -> ABu, accumulate squeeze ----
    float asum = 0.f;
    if (act) {
        const int i = lj;
        const int j0 = seg * 28;
        const float xm = cst[6], xi = cst[7], xmxi = cst[8];
        const int ci = c0 + cc;
        const float g = gam[ci], be = bet[ci], bm = bnm[ci];
        const float rsv = rsqrtf(bnv[ci] + 1e-3f);
        const float A1c = g * rsv, A0c = be - g * bm * rsv;
        const float C1 = -A1c * (LOG2E * 0.1f);
        const float C0 = -A0c * LOG2E;
        const float d0 = cst[0], d1 = cst[1], d2 = cst[2], d3 = cst[3], d4 = cst[4], nd = cst[5];
        const float* sp = SATl + cc;

        auto mkU = [&](int hk) {
            ScaleU uu;
            int y1g = min(i + hk, 55) + 1;
            int y0g = max(i - hk + 1, 0);
            uu.rb1 = y1g * 456; uu.rb0 = y0g * 456;
            uu.xmch = xm * (float)(y1g - y0g);
            return uu;
        };
        const ScaleU u0 = mkU(1), u1 = mkU(2), u2 = mkU(4), u3 = mkU(8), u4 = mkU(16);

        auto meas = [&](int j, const ScaleU& uu, int hk) -> float {
            int x1g = min(j + hk, 55) + 1;
            int x0g = max(j - hk + 1, 0);
            float cw = (float)(x1g - x0g);
            int o1 = x1g << 3, o0 = x0g << 3;
            float s = sp[uu.rb1 + o1] - sp[uu.rb0 + o1] - sp[uu.rb1 + o0] + sp[uu.rb0 + o0];
            return __log2f(fmaxf((s - uu.xmch * cw) * xi, 0.f) + 1e-7f);
        };

        const float* xrow = x + b * NPERB + i * 7168 + c0 + cc;
        unsigned int* abrow = ABu + b * NPERB + i * 7168 + c0 + cc;
        for (int jj = 0; jj < 28; jj++) {
            int j = j0 + jj;
            float l0 = meas(j, u0, 1);
            float l1 = meas(j, u1, 2);
            float l2 = meas(j, u2, 4);
            float l3 = meas(j, u3, 8);
            float l4 = meas(j, u4, 16);
            float w2 = -2.f * l0 - l1 + l3 + 2.f * l4;
            asum += w2;
            float alphas = w2 * 0.1f;
            float mean = 0.2f * (l0 + l1 + l2 + l3 + l4);
            float a0 = l0 - mean, a1 = l1 - mean, a2 = l2 - mean, a3 = l3 - mean, a4 = l4 - mean;
            float na2  = a0 * a0 + a1 * a1 + a2 * a2 + a3 * a3 + a4 * a4;
            float adot = a0 * d0 + a1 * d1 + a2 * d2 + a3 * d3 + a4 * d4;
            float na = __builtin_amdgcn_sqrtf(na2);
            float cosv = (alphas * adot) * __builtin_amdgcn_rcpf(na * fabsf(alphas) * nd + 1e-7f);
            float sim = 0.5f * (cosv + 1.f);
            float sbn = __builtin_amdgcn_rcpf(1.f + exp2f(C1 * w2 + C0));
            float xs = fmaf(xrow[j * 128], xi, -xmxi);
            float A = sim * sbn;
            float B = (1.f - sim) * xs;
            abrow[j * 128] = __builtin_bit_cast(unsigned int, __floats2half2_rn(A, B));
        }
    }
    // squeeze reduce: lanes l and l+8 share cc (896 = 14 full waves)
    asum += __shfl_down(asum, 32);
    asum += __shfl_down(asum, 16);
    asum += __shfl_down(asum, 8);
    {
        int w = tid >> 6, l = tid & 63;
        if (w < 14 && l < 8) wsum[w * 8 + l] = asum;
    }
    __syncthreads();
    if (tid < 8) {
        float s = 0.f;
#pragma unroll
        for (int w = 0; w < 14; w++) s += wsum[w * 8 + tid];
        atomicAdd(&sq[b * 128 + c0 + tid], s * 0.1f);
    }
}

// ---------- K2: SE + mix (XCD-affine: b = p&15) ----------
__launch_bounds__(256)
__global__ void k_mix2(const unsigned int* __restrict__ ABu, const float* __restrict__ sq,
                       const float* __restrict__ W1, const float* __restrict__ b1,
                       const float* __restrict__ W2, const float* __restrict__ b2,
                       float* __restrict__ out) {
    __shared__ float sqz[128];
    __shared__ float hid[16];
    __shared__ float exc[128];
    int p = blockIdx.x;
    int b = p & 15, chunk = p >> 4;     // 64 chunks per sample
    int tid = threadIdx.x;
    if (tid < 128) sqz[tid] = sq[b * 128 + tid] * (1.f / 3136.f);
    __syncthreads();
    if (tid < 16) {
        float acc = b1[tid];
        for (int c2 = 0; c2 < 128; c2++) acc += sqz[c2] * W1[c2 * 16 + tid];
        hid[tid] = fmaxf(acc, 0.f);
    }
    __syncthreads();
    if (tid < 128) {
        float acc = b2[tid];
#pragma unroll
        for (int h = 0; h < 16; h++) acc += hid[h] * W2[h * 128 + tid];
        exc[tid] = sigmoidf_fast(acc);
    }
    __syncthreads();
    const uint4* ab4 = (const uint4*)ABu;
    float4* out4 = (float4*)out;
    const int base = b * NQ + chunk * 1568;
    for (int q = tid; q < 1568; q += 256) {
        int g = base + q;
        int cb = (g & 31) << 2;
        uint4 u = ab4[g];
        float2 p0 = __half22float2(__builtin_bit_cast(__half2, u.x));
        float2 p1 = __half22float2(__builtin_bit_cast(__half2, u.y));
        float2 p2 = __half22float2(__builtin_bit_cast(__half2, u.z));
        float2 p3 = __half22float2(__builtin_bit_cast(__half2, u.w));
        out4[g] = make_float4(p0.x + p0.y * exc[cb],
                              p1.x + p1.y * exc[cb + 1],
                              p2.x + p2.y * exc[cb + 2],
                              p3.x + p3.y * exc[cb + 3]);
    }
}

extern "C" void kernel_launch(void* const* d_in, const int* in_sizes, int n_in,
                              void* d_out, int out_size, void* d_ws, size_t ws_size,
                              hipStream_t stream) {
    const float* x   = (const float*)d_in[0];
    const float* kap = (const float*)d_in[1];
    const float* W1  = (const float*)d_in[2];
    const float* b1  = (const float*)d_in[3];
    const float* W2  = (const float*)d_in[4];
    const float* b2  = (const float*)d_in[5];
    const float* gam = (const float*)d_in[6];
    const float* bet = (const float*)d_in[7];
    const float* bnm = (const float*)d_in[8];
    const float* bnv = (const float*)d_in[9];
    float* out = (float*)d_out;

    float*    sq   = (float*)d_ws;                 // 2048
    unsigned* pmnu = (unsigned*)(sq + 2048);       // 16
    unsigned* pmxu = pmnu + 16;                    // 16
    unsigned* ABu  = (unsigned*)(pmxu + 16);       // NTOT u32 (16B-aligned: offset 8320)

    hipMemsetAsync(sq, 0, 2048 * sizeof(float), stream);
    hipMemsetAsync(pmnu, 0xFF, 16 * sizeof(unsigned), stream);
    hipMemsetAsync(pmxu, 0x00, 16 * sizeof(unsigned), stream);

    k_minmax<<<512, 256, 0, stream>>>((const float4*)x, pmnu, pmxu);
    k_satg<<<256, 1024, 0, stream>>>(x, kap, gam, bet, bnm, bnv, pmnu, pmxu, sq, ABu);
    k_mix2<<<1024, 256, 0, stream>>>(ABu, sq, W1, b1, W2, b2, out);
}